// Round 7
// baseline (825.841 us; speedup 1.0000x reference)
//
#include <hip/hip_runtime.h>

// Problem constants
constexpr int Dm = 1024;
constexpr int NH = 16;
constexpr int Ff = 2048;
constexpr int NE = 8;
constexpr int Bn = 4;
constexpr int Tn = 512;
constexpr int Nt = 2048;   // total tokens

typedef float  f32x4  __attribute__((ext_vector_type(4)));
typedef __bf16 bf16x8 __attribute__((ext_vector_type(8)));
typedef unsigned short u16x8 __attribute__((ext_vector_type(8)));

// fp32 -> bf16 round-to-nearest-even
__device__ inline unsigned short f2bf(float f) {
    unsigned u = __builtin_bit_cast(unsigned, f);
    u += 0x7FFFu + ((u >> 16) & 1u);
    return (unsigned short)(u >> 16);
}
__device__ inline float bf2f(unsigned short h) {
    unsigned u = (unsigned)h << 16;
    return __builtin_bit_cast(float, u);
}
__device__ inline void splitbf(float x, unsigned short& hi, unsigned short& lo) {
    hi = f2bf(x);
    lo = f2bf(x - bf2f(hi));
}
__device__ inline bf16x8 ld_frag(const unsigned short* p) {
    return __builtin_bit_cast(bf16x8, *(const u16x8*)p);
}

// ---------------------------------------------------------------------------
// MFMA GEMM, tile 64x128x32 (M-tile halved vs r6 to double active blocks:
// latency-bound regime needs waves-in-flight, not per-block cleverness).
// 4 waves as 2x2; each wave 32x64 = 2x4 MFMA tiles.
//  SPLIT: 3-term split-bf16 (fp32-grade) vs single bf16.
//  ABF:   A is pre-converted bf16. CBF: C written bf16.
//  ACC:   epilogue does accOut[token] += gate[pid]*val (MoE combine fused).
// Straight-line staging (round-5 form — compiler schedules it best).
// Optional fused second dense GEMM (blockIdx.x >= xSplit -> descriptor 2).
// ---------------------------------------------------------------------------
template <int SPLIT, int ABF, int CBF, int ACC>
__global__ __launch_bounds__(256) void gemm_bf16_kernel(
    const void* __restrict__ Ain, int lda,
    const float* __restrict__ W0, const float* __restrict__ W1,
    const float* __restrict__ W2, int ldw, size_t weStride,
    const float* __restrict__ B0, const float* __restrict__ B1,
    const float* __restrict__ B2, size_t beStride,
    void* __restrict__ Cout, int ldc,
    int Mparam, int K,
    const int* __restrict__ lst, int lstStride, const int* __restrict__ cnt,
    int mode, int relu,
    const void* __restrict__ Ain2, const float* __restrict__ W0b,
    const float* __restrict__ W1b, const float* __restrict__ B0b,
    const float* __restrict__ B1b, void* __restrict__ Cout2, int ldc2,
    int xSplit,
    const float* __restrict__ gatep, float* __restrict__ accOut)
{
    __shared__ __align__(16) unsigned short AsH[64 * 40];
    __shared__ __align__(16) unsigned short WsH[128 * 40];
    __shared__ __align__(16) unsigned short AsL[SPLIT ? 64 * 40 : 1];
    __shared__ __align__(16) unsigned short WsL[SPLIT ? 128 * 40 : 1];
    __shared__ int inIdx[64];
    __shared__ int outIdx[64];

    const int e = blockIdx.z;
    const int M = (mode == 0) ? Mparam : cnt[e];
    const int m0 = blockIdx.y * 64;
    if (m0 >= M) return;

    // select primary or fused-second descriptor
    int bx = blockIdx.x;
    const void* Aptr = Ain;
    void* Cptr = Cout;
    int myldc = ldc;
    const float *w0 = W0, *w1 = W1, *w2 = W2, *b0 = B0, *b1 = B1, *b2 = B2;
    if (xSplit && bx >= xSplit) {
        bx -= xSplit;
        Aptr = Ain2; Cptr = Cout2; myldc = ldc2;
        w0 = W0b; w1 = W1b; w2 = W1b; b0 = B0b; b1 = B1b; b2 = B1b;
    }
    const int n0 = bx * 128;
    const int seg = n0 >> 10;
    const float* W = ((seg == 0) ? w0 : (seg == 1) ? w1 : w2) + (size_t)e * weStride;
    const float* bias = ((seg == 0) ? b0 : (seg == 1) ? b1 : b2) + (size_t)e * beStride;
    const int nseg = n0 & 1023;
    const int tid = threadIdx.x;

    if (tid < 64) {
        int g = m0 + tid;
        bool valid = g < M;
        int gi, go;
        if (mode == 0) { gi = valid ? g : (M - 1); go = valid ? g : -1; }
        else {
            int pid = lst[(size_t)e * lstStride + (valid ? g : 0)];
            gi = (mode == 1) ? (pid >> 1) : pid;
            go = valid ? pid : -1;
        }
        inIdx[tid] = gi;
        outIdx[tid] = go;
    }
    __syncthreads();

    const int ar = tid >> 2, ahalf = tid & 3;                  // A: 4 thr/row, 8 el each
    const int bn = (tid & 63) * 2, bko = ((tid >> 6) & 3) * 8; // B: 2 n, 8 k
    const float* aBaseF = ABF ? nullptr
        : ((const float*)Aptr + (size_t)inIdx[ar] * lda + ahalf * 8);
    const unsigned short* aBaseB = ABF
        ? ((const unsigned short*)Aptr + (size_t)inIdx[ar] * lda + ahalf * 8)
        : nullptr;
    const float* wBase = W + (size_t)bko * ldw + nseg + bn;

    const int lane = tid & 63, wv = tid >> 6;
    const int wy = (wv >> 1) * 32, wx = (wv & 1) * 64;
    const int l15 = lane & 15, quad = lane >> 4;

    f32x4 acc[2][4];
    #pragma unroll
    for (int i = 0; i < 2; ++i)
        #pragma unroll
        for (int j = 0; j < 4; ++j) acc[i][j] = (f32x4)0.f;

    for (int k0 = 0; k0 < K; k0 += 32) {
        // ---- stage A tile [m][k] ----
        if (ABF) {
            const unsigned short* ap = aBaseB + k0;
            *(u16x8*)&AsH[ar * 40 + ahalf * 8] = *(const u16x8*)(ap);
        } else {
            const float* ap = aBaseF + k0;
            float v[8];
            *(float4*)&v[0] = *(const float4*)(ap);
            *(float4*)&v[4] = *(const float4*)(ap + 4);
            u16x8 h0, l0;
            #pragma unroll
            for (int i = 0; i < 8; ++i) {
                if (SPLIT) {
                    unsigned short hh, ll;
                    splitbf(v[i], hh, ll); h0[i] = hh; l0[i] = ll;
                } else {
                    h0[i] = f2bf(v[i]);
                }
            }
            *(u16x8*)&AsH[ar * 40 + ahalf * 8] = h0;
            if (SPLIT) *(u16x8*)&AsL[ar * 40 + ahalf * 8] = l0;
        }
        // ---- stage W tile transposed [n][k] ----
        {
            const float* wp = wBase + (size_t)k0 * ldw;
            float2 wr[8];
            #pragma unroll
            for (int j = 0; j < 8; ++j) wr[j] = *(const float2*)(wp + (size_t)j * ldw);
            u16x8 h0, h1, l0, l1;
            #pragma unroll
            for (int j = 0; j < 8; ++j) {
                if (SPLIT) {
                    unsigned short hh, ll;
                    splitbf(wr[j].x, hh, ll); h0[j] = hh; l0[j] = ll;
                    splitbf(wr[j].y, hh, ll); h1[j] = hh; l1[j] = ll;
                } else {
                    h0[j] = f2bf(wr[j].x);
                    h1[j] = f2bf(wr[j].y);
                }
            }
            *(u16x8*)&WsH[bn * 40 + bko]       = h0;
            *(u16x8*)&WsH[(bn + 1) * 40 + bko] = h1;
            if (SPLIT) {
                *(u16x8*)&WsL[bn * 40 + bko]       = l0;
                *(u16x8*)&WsL[(bn + 1) * 40 + bko] = l1;
            }
        }
        __syncthreads();
        // ---- fragments + MFMA ----
        bf16x8 ah[2], bh[4], al[2], bl[4];
        #pragma unroll
        for (int mi = 0; mi < 2; ++mi)
            ah[mi] = ld_frag(&AsH[(wy + mi * 16 + l15) * 40 + quad * 8]);
        #pragma unroll
        for (int ni = 0; ni < 4; ++ni)
            bh[ni] = ld_frag(&WsH[(wx + ni * 16 + l15) * 40 + quad * 8]);
        if (SPLIT) {
            #pragma unroll
            for (int mi = 0; mi < 2; ++mi)
                al[mi] = ld_frag(&AsL[(wy + mi * 16 + l15) * 40 + quad * 8]);
            #pragma unroll
            for (int ni = 0; ni < 4; ++ni)
                bl[ni] = ld_frag(&WsL[(wx + ni * 16 + l15) * 40 + quad * 8]);
        }
        #pragma unroll
        for (int mi = 0; mi < 2; ++mi)
            #pragma unroll
            for (int ni = 0; ni < 4; ++ni) {
                acc[mi][ni] = __builtin_amdgcn_mfma_f32_16x16x32_bf16(
                    ah[mi], bh[ni], acc[mi][ni], 0, 0, 0);
                if (SPLIT) {
                    acc[mi][ni] = __builtin_amdgcn_mfma_f32_16x16x32_bf16(
                        ah[mi], bl[ni], acc[mi][ni], 0, 0, 0);
                    acc[mi][ni] = __builtin_amdgcn_mfma_f32_16x16x32_bf16(
                        al[mi], bh[ni], acc[mi][ni], 0, 0, 0);
                }
            }
        __syncthreads();
    }

    // ---- epilogue ----
    #pragma unroll
    for (int mi = 0; mi < 2; ++mi) {
        #pragma unroll
        for (int r = 0; r < 4; ++r) {
            int rl = wy + mi * 16 + quad * 4 + r;
            int orow = outIdx[rl];
            if (orow < 0) continue;
            #pragma unroll
            for (int ni = 0; ni < 4; ++ni) {
                int col = n0 + wx + ni * 16 + l15;
                float val = acc[mi][ni][r] + bias[col & 1023];
                if (relu) val = fmaxf(val, 0.f);
                if (ACC) {
                    float g = gatep[orow];
                    atomicAdd(&accOut[(size_t)(orow >> 1) * Dm + col], g * val);
                } else if (CBF) {
                    ((unsigned short*)Cptr)[(size_t)orow * myldc + col] = f2bf(val);
                } else {
                    ((float*)Cptr)[(size_t)orow * myldc + col] = val;
                }
            }
        }
    }
}

// ---------------------------------------------------------------------------
// Split-bf16 flash attention. Block = 64 Q rows x (b,h); 4 waves x 16 Q rows.
// ---------------------------------------------------------------------------
__global__ __launch_bounds__(256) void attn_kernel(
    const float* __restrict__ Qp, int qld,
    const float* __restrict__ Kp, int kld, int kOff,
    const float* __restrict__ Vp, int vld, int vOff,
    float* __restrict__ O)
{
    __shared__ __align__(16) unsigned short KtH[64 * 72], KtL[64 * 72];
    __shared__ __align__(16) unsigned short VtH[64 * 72], VtL[64 * 72];
    __shared__ __align__(16) unsigned short PtH[4][16 * 72], PtL[4][16 * 72];

    const int tid = threadIdx.x, lane = tid & 63, wv = tid >> 6;
    const int quad = lane >> 4, l15 = lane & 15;
    const int b = blockIdx.z, h = blockIdx.y, q0 = blockIdx.x * 64;
    const int bT = b * Tn;

    bf16x8 aqh[2], aql[2];
    {
        const float* qp = Qp + (size_t)(bT + q0 + wv * 16 + l15) * qld + h * 64;
        #pragma unroll
        for (int s = 0; s < 2; ++s) {
            float v[8];
            *(float4*)&v[0] = *(const float4*)(qp + s * 32 + quad * 8);
            *(float4*)&v[4] = *(const float4*)(qp + s * 32 + quad * 8 + 4);
            u16x8 th, tl;
            #pragma unroll
            for (int i = 0; i < 8; ++i) {
                unsigned short hh, ll;
                splitbf(v[i], hh, ll); th[i] = hh; tl[i] = ll;
            }
            aqh[s] = __builtin_bit_cast(bf16x8, th);
            aql[s] = __builtin_bit_cast(bf16x8, tl);
        }
    }

    f32x4 oacc[4];
    #pragma unroll
    for (int i = 0; i < 4; ++i) oacc[i] = (f32x4)0.f;
    float mrow[4] = {-1e30f, -1e30f, -1e30f, -1e30f};
    float lrow[4] = {0.f, 0.f, 0.f, 0.f};

    const int rr = tid >> 2, cc = tid & 3;

    for (int kt0 = 0; kt0 < Tn; kt0 += 64) {
        // ---- stage K [kt][d] hi/lo, V transposed [d][kt] hi/lo ----
        {
            const float* kr = Kp + (size_t)(bT + kt0 + rr) * kld + kOff + h * 64 + cc * 16;
            float v[16];
            *(float4*)&v[0]  = *(const float4*)(kr);
            *(float4*)&v[4]  = *(const float4*)(kr + 4);
            *(float4*)&v[8]  = *(const float4*)(kr + 8);
            *(float4*)&v[12] = *(const float4*)(kr + 12);
            u16x8 h0, h1, l0, l1;
            #pragma unroll
            for (int i = 0; i < 8; ++i) {
                unsigned short hh, ll;
                splitbf(v[i], hh, ll); h0[i] = hh; l0[i] = ll;
                splitbf(v[8 + i], hh, ll); h1[i] = hh; l1[i] = ll;
            }
            *(u16x8*)&KtH[rr * 72 + cc * 16]     = h0;
            *(u16x8*)&KtH[rr * 72 + cc * 16 + 8] = h1;
            *(u16x8*)&KtL[rr * 72 + cc * 16]     = l0;
            *(u16x8*)&KtL[rr * 72 + cc * 16 + 8] = l1;

            const float* vr = Vp + (size_t)(bT + kt0 + rr) * vld + vOff + h * 64 + cc * 16;
            float fv[16];
            *(float4*)&fv[0]  = *(const float4*)(vr);
            *(float4*)&fv[4]  = *(const float4*)(vr + 4);
            *(float4*)&fv[8]  = *(const float4*)(vr + 8);
            *(float4*)&fv[12] = *(const float4*)(vr + 12);
            #pragma unroll
            for (int i = 0; i < 16; ++i) {
                unsigned short hh, ll;
                splitbf(fv[i], hh, ll);
                VtH[(cc * 16 + i) * 72 + rr] = hh;
                VtL[(cc * 16 + i) * 72 + rr] = ll;
            }
        }
        __syncthreads();

        // ---- S = (Q K^T) * 0.125, split 3-term ----
        f32x4 sacc[4];
        #pragma unroll
        for (int nt = 0; nt < 4; ++nt) {
            sacc[nt] = (f32x4)0.f;
            #pragma unroll
            for (int s = 0; s < 2; ++s) {
                bf16x8 bkh = ld_frag(&KtH[(nt * 16 + l15) * 72 + s * 32 + quad * 8]);
                bf16x8 bkl = ld_frag(&KtL[(nt * 16 + l15) * 72 + s * 32 + quad * 8]);
                sacc[nt] = __builtin_amdgcn_mfma_f32_16x16x32_bf16(aqh[s], bkh, sacc[nt], 0, 0, 0);
                sacc[nt] = __builtin_amdgcn_mfma_f32_16x16x32_bf16(aqh[s], bkl, sacc[nt], 0, 0, 0);
                sacc[nt] = __builtin_amdgcn_mfma_f32_16x16x32_bf16(aql[s], bkh, sacc[nt], 0, 0, 0);
            }
        }
        #pragma unroll
        for (int nt = 0; nt < 4; ++nt)
            #pragma unroll
            for (int r = 0; r < 4; ++r) sacc[nt][r] *= 0.125f;

        // ---- online softmax ----
        float alpha[4], mnew[4];
        #pragma unroll
        for (int r = 0; r < 4; ++r) {
            float mx = fmaxf(fmaxf(sacc[0][r], sacc[1][r]), fmaxf(sacc[2][r], sacc[3][r]));
            #pragma unroll
            for (int msk = 1; msk < 16; msk <<= 1) mx = fmaxf(mx, __shfl_xor(mx, msk));
            mnew[r] = fmaxf(mrow[r], mx);
            alpha[r] = __expf(mrow[r] - mnew[r]);
            mrow[r] = mnew[r];
        }
        float rs[4] = {0.f, 0.f, 0.f, 0.f};
        #pragma unroll
        for (int nt = 0; nt < 4; ++nt)
            #pragma unroll
            for (int r = 0; r < 4; ++r) {
                float p = __expf(sacc[nt][r] - mnew[r]);
                sacc[nt][r] = p;
                rs[r] += p;
            }
        #pragma unroll
        for (int r = 0; r < 4; ++r) {
            #pragma unroll
            for (int msk = 1; msk < 16; msk <<= 1) rs[r] += __shfl_xor(rs[r], msk);
            lrow[r] = lrow[r] * alpha[r] + rs[r];
        }
        #pragma unroll
        for (int ni = 0; ni < 4; ++ni)
            #pragma unroll
            for (int r = 0; r < 4; ++r) oacc[ni][r] *= alpha[r];

        // ---- P: C-layout -> A-layout via per-wave LDS (hi/lo) ----
        #pragma unroll
        for (int nt = 0; nt < 4; ++nt)
            #pragma unroll
            for (int r = 0; r < 4; ++r) {
                unsigned short hh, ll;
                splitbf(sacc[nt][r], hh, ll);
                PtH[wv][(quad * 4 + r) * 72 + nt * 16 + l15] = hh;
                PtL[wv][(quad * 4 + r) * 72 + nt * 16 + l15] = ll;
            }
        asm volatile("s_waitcnt lgkmcnt(0)" ::: "memory");

        // ---- O += P @ V, split 3-term ----
        #pragma unroll
        for (int s = 0; s < 2; ++s) {
            bf16x8 aph = ld_frag(&PtH[wv][l15 * 72 + s * 32 + quad * 8]);
            bf16x8 apl = ld_frag(&PtL[wv][l15 * 72 + s * 32 + quad * 8]);
            #pragma unroll
            for (int ni = 0; ni < 4; ++ni) {
                bf16x8 bvh = ld_frag(&VtH[(ni * 16 + l15) * 72 + s * 32 + quad * 8]);
                bf16x8 bvl = ld_frag(&VtL[(ni * 16 + l15) * 72 + s * 32 + quad * 8]);
                oacc[ni] = __builtin_amdgcn_mfma_f32_16x16x32_bf16(aph, bvh, oacc[ni], 0, 0, 0);
                oacc[ni] = __builtin_amdgcn_mfma_f32_16x16x32_bf16(aph, bvl, oacc[ni], 0, 0, 0);
                oacc[ni] = __builtin_amdgcn_mfma_f32_16x16x32_bf16(apl, bvh, oacc[ni], 0, 0, 0);
            }
        }
        __syncthreads();
    }

    #pragma unroll
    for (int r = 0; r < 4; ++r) {
        float inv = 1.f / lrow[r];
        int orow = bT + q0 + wv * 16 + quad * 4 + r;
        #pragma unroll
        for (int ni = 0; ni < 4; ++ni) {
            int col = h * 64 + ni * 16 + l15;
            O[(size_t)orow * Dm + col] = oacc[ni][r] * inv;
        }
    }
}

// ---------------------------------------------------------------------------
// Fused residual + LayerNorm
// ---------------------------------------------------------------------------
__global__ __launch_bounds__(256) void ln_residual_kernel(
    const float* __restrict__ X, const float* __restrict__ R,
    const float* __restrict__ g, const float* __restrict__ bta,
    float* __restrict__ Out)
{
    __shared__ float red[8];
    const int t = blockIdx.x, tid = threadIdx.x;
    float v[4];
    float s = 0.f;
    #pragma unroll
    for (int i = 0; i < 4; ++i) {
        int c = tid + i * 256;
        v[i] = X[(size_t)t * Dm + c] + R[(size_t)t * Dm + c];
        s += v[i];
    }
    #pragma unroll
    for (int off = 32; off; off >>= 1) s += __shfl_down(s, off);
    const int wid = tid >> 6;
    if ((tid & 63) == 0) red[wid] = s;
    __syncthreads();
    const float mean = (red[0] + red[1] + red[2] + red[3]) * (1.f / 1024.f);
    float s2 = 0.f;
    #pragma unroll
    for (int i = 0; i < 4; ++i) { float d = v[i] - mean; s2 += d * d; }
    #pragma unroll
    for (int off = 32; off; off >>= 1) s2 += __shfl_down(s2, off);
    if ((tid & 63) == 0) red[4 + wid] = s2;
    __syncthreads();
    const float var  = (red[4] + red[5] + red[6] + red[7]) * (1.f / 1024.f);
    const float rstd = rsqrtf(var + 1e-5f);
    #pragma unroll
    for (int i = 0; i < 4; ++i) {
        int c = tid + i * 256;
        Out[(size_t)t * Dm + c] = (v[i] - mean) * rstd * g[c] + bta[c];
    }
}

// ---------------------------------------------------------------------------
// MoE router — LDS-aggregated stats, block-batched atomics.
// ---------------------------------------------------------------------------
constexpr int RT_TPB = 32;   // tokens per block
__global__ __launch_bounds__(256) void router_kernel(
    const float* __restrict__ X, const float* __restrict__ rw,
    const float* __restrict__ rb, float* __restrict__ gatep,
    int* __restrict__ elist, int* __restrict__ ecnt,
    float* __restrict__ impf, float* __restrict__ cntf)
{
    __shared__ float simp[NE];
    __shared__ int   scnt[NE];
    __shared__ int   sbase[NE];
    __shared__ int   sexp[RT_TPB][2];
    __shared__ int   spos[RT_TPB][2];

    const int tid = threadIdx.x, lane = tid & 63, wv = tid >> 6;
    if (tid < NE) { simp[tid] = 0.f; scnt[tid] = 0; }
    __syncthreads();

    const int t0 = blockIdx.x * RT_TPB;

    for (int i = 0; i < 8; ++i) {
        const int slot = wv * 8 + i;
        const int t = t0 + slot;
        float l[NE];
        #pragma unroll
        for (int e = 0; e < NE; ++e) l[e] = 0.f;
        #pragma unroll
        for (int j = 0; j < Dm / 64; ++j) {
            int d = lane + j * 64;
            float x = X[(size_t)t * Dm + d];
            #pragma unroll
            for (int e = 0; e < NE; ++e) l[e] += x * rw[d * NE + e];
        }
        #pragma unroll
        for (int e = 0; e < NE; ++e) {
            float vv = l[e];
            #pragma unroll
            for (int off = 32; off; off >>= 1) vv += __shfl_down(vv, off);
            l[e] = vv;
        }
        if (lane == 0) {
            float mx = -1e30f;
            #pragma unroll
            for (int e = 0; e < NE; ++e) { l[e] += rb[e]; mx = fmaxf(mx, l[e]); }
            float p[NE];
            float sum = 0.f;
            #pragma unroll
            for (int e = 0; e < NE; ++e) { p[e] = __expf(l[e] - mx); sum += p[e]; }
            const float inv = 1.f / sum;
            int e0 = 0, e1 = 0;
            float v0 = -1.f, v1 = -1.f;
            #pragma unroll
            for (int e = 0; e < NE; ++e) {
                float pe = p[e] * inv;
                atomicAdd(&simp[e], pe);
                if (pe > v0)      { v1 = v0; e1 = e0; v0 = pe; e0 = e; }
                else if (pe > v1) { v1 = pe; e1 = e; }
            }
            const float gs = 1.f / (v0 + v1);
            sexp[slot][0] = e0;
            sexp[slot][1] = e1;
            spos[slot][0] = atomicAdd(&scnt[e0], 1);
            spos[slot][1] = atomicAdd(&scnt[e1], 1);
            gatep[2 * t]     = v0 * gs;
            gatep[2 * t + 1] = v1 * gs;
        }
    }
    __syncthreads();

    if (tid < NE) {
        sbase[tid] = atomicAdd(&ecnt[tid], scnt[tid]);
        atomicAdd(&impf[tid], simp[tid]);
        atomicAdd(&cntf[tid], (float)scnt[tid]);
    }
    __syncthreads();

    if (tid < RT_TPB * 2) {
        const int slot = tid >> 1, k = tid & 1;
        const int e = sexp[slot][k];
        elist[e * Nt + sbase[e] + spos[slot][k]] = 2 * (t0 + slot) + k;
    }
}

// zero t2 accumulator (+ MoE stats on block 0)
__global__ __launch_bounds__(256) void zero_kernel(
    float* __restrict__ t2, int* __restrict__ ecnt,
    float* __restrict__ impf, float* __restrict__ cntf)
{
    int i = blockIdx.x * 256 + threadIdx.x;
    *(float4*)&t2[(size_t)i * 4] = make_float4(0.f, 0.f, 0.f, 0.f);
    if (blockIdx.x == 0 && threadIdx.x < NE) {
        ecnt[threadIdx.x] = 0;
        impf[threadIdx.x] = 0.f;
        cntf[threadIdx.x] = 0.f;
    }
}

__global__ void lb_kernel(const float* __restrict__ impf,
                          const float* __restrict__ cntf,
                          float* __restrict__ out)
{
    if (threadIdx.x == 0) {
        float s = 0.f;
        for (int e = 0; e < NE; ++e) s += cntf[e] * impf[e];
        out[0] = (float)NE * s / ((float)Nt * 2.f * (float)Nt);
    }
}

// ---------------------------------------------------------------------------
extern "C" void kernel_launch(void* const* d_in, const int* in_sizes, int n_in,
                              void* d_out, int out_size, void* d_ws, size_t ws_size,
                              hipStream_t stream)
{
    const float* tgt   = (const float*)d_in[0];
    const float* memry = (const float*)d_in[1];
    const float* sa_wq = (const float*)d_in[2];
    const float* sa_wk = (const float*)d_in[3];
    const float* sa_wv = (const float*)d_in[4];
    const float* sa_wo = (const float*)d_in[5];
    const float* ca_wq = (const float*)d_in[6];
    const float* ca_wk = (const float*)d_in[7];
    const float* ca_wv = (const float*)d_in[8];
    const float* ca_wo = (const float*)d_in[9];
    const float* sa_bq = (const float*)d_in[10];
    const float* sa_bk = (const float*)d_in[11];
    const float* sa_bv = (const float*)d_in[12];
    const float* sa_bo = (const float*)d_in[13];
    const float* ca_bq = (const float*)d_in[14];
    const float* ca_bk = (const float*)d_in[15];
    const float* ca_bv = (const float*)d_in[16];
    const float* ca_bo = (const float*)d_in[17];
    const float* ln1_g = (const float*)d_in[18];
    const float* ln2_g = (const float*)d_in[19];
    const float* ln3_g = (const float*)d_in[20];
    const float* ln1_b = (const float*)d_in[21];
    const float* ln2_b = (const float*)d_in[22];
    const float* ln3_b = (const float*)d_in[23];
    const float* rw    = (const float*)d_in[24];
    const float* rb    = (const float*)d_in[25];
    const float* w1    = (const float*)d_in[26];
    const float* b1    = (const float*)d_in[27];
    const float* w2    = (const float*)d_in[28];
    const float* b2    = (const float*)d_in[29];

    float* ws = (float*)d_ws;
    const size_t ND = (size_t)Nt * Dm;
    float* qkv  = ws;                         // [0,3) self QKV
    float* qc   = ws;                         // [0,1) cross Q (after self phase)
    unsigned short* hbuf16 = (unsigned short*)ws;  // [0,2) as u16: 4096 x Ff bf16
    float* attnO = ws + 3 * ND;               // [3,4)
    float* t2   = ws + 4 * ND;                // [4,5)  (also MoE accumulator)
    float* tb   = ws + 5 * ND;                // [5,6)
    float* kvc  = ws + 6 * ND;                // [6,8) cross K/V
    float* gatep = ws + 8 * ND;               // 2*Nt
    int*   elist = (int*)(gatep + 2 * Nt);    // NE*Nt
    int*   ecnt  = elist + NE * Nt;           // NE
    float* impf  = (float*)(ecnt + NE);       // NE
    float* cntf  = impf + NE;                 // NE
    float* outp  = (float*)d_out;

    dim3 blk(256);
    dim3 attnGrid(Tn / 64, NH, Bn);

    // ---- fused: self QKV (x<24) + cross KV (x>=24); M-tile 64 -> y=32 ----
    gemm_bf16_kernel<1, 0, 0, 0><<<dim3(40, 32, 1), blk, 0, stream>>>(
        tgt, Dm, sa_wq, sa_wk, sa_wv, Dm, 0, sa_bq, sa_bk, sa_bv, 0,
        qkv, 3 * Dm, Nt, Dm, nullptr, 0, nullptr, 0, 0,
        memry, ca_wk, ca_wv, ca_bk, ca_bv, kvc, 2 * Dm, 24,
        nullptr, nullptr);
    attn_kernel<<<attnGrid, blk, 0, stream>>>(
        qkv, 3 * Dm, qkv, 3 * Dm, 1024, qkv, 3 * Dm, 2048, attnO);
    gemm_bf16_kernel<1, 0, 0, 0><<<dim3(8, 32, 1), blk, 0, stream>>>(
        attnO, Dm, sa_wo, sa_wo, sa_wo, Dm, 0, sa_bo, sa_bo, sa_bo, 0,
        t2, Dm, Nt, Dm, nullptr, 0, nullptr, 0, 0,
        nullptr, nullptr, nullptr, nullptr, nullptr, nullptr, 0, 0,
        nullptr, nullptr);
    ln_residual_kernel<<<Nt, blk, 0, stream>>>(tgt, t2, ln1_g, ln1_b, tb);

    // ---- cross-attention ----
    gemm_bf16_kernel<1, 0, 0, 0><<<dim3(8, 32, 1), blk, 0, stream>>>(
        tb, Dm, ca_wq, ca_wq, ca_wq, Dm, 0, ca_bq, ca_bq, ca_bq, 0,
        qc, Dm, Nt, Dm, nullptr, 0, nullptr, 0, 0,
        nullptr, nullptr, nullptr, nullptr, nullptr, nullptr, 0, 0,
        nullptr, nullptr);
    attn_kernel<<<attnGrid, blk, 0, stream>>>(
        qc, Dm, kvc, 2 * Dm, 0, kvc, 2 * Dm, 1024, attnO);
    gemm_bf16_kernel<1, 0, 0, 0><<<dim3(8, 32, 1), blk, 0, stream>>>(
        attnO, Dm, ca_wo, ca_wo, ca_wo, Dm, 0, ca_bo, ca_bo, ca_bo, 0,
        t2, Dm, Nt, Dm, nullptr, 0, nullptr, 0, 0,
        nullptr, nullptr, nullptr, nullptr, nullptr, nullptr, 0, 0,
        nullptr, nullptr);
    ln_residual_kernel<<<Nt, blk, 0, stream>>>(tb, t2, ln2_g, ln2_b, tb);

    // ---- MoE ----
    zero_kernel<<<(Nt * Dm) / 1024, blk, 0, stream>>>(t2, ecnt, impf, cntf);
    router_kernel<<<Nt / RT_TPB, blk, 0, stream>>>(tb, rw, rb, gatep, elist, ecnt, impf, cntf);
    // ffn1: H[pid] = relu(tb[pid>>1] @ w1[e] + b1[e]) -> bf16
    gemm_bf16_kernel<0, 0, 1, 0><<<dim3(16, 32, 8), blk, 0, stream>>>(
        tb, Dm, w1, w1 + 1024, w1 + 1024, Ff, (size_t)Dm * Ff, b1, b1 + 1024, b1 + 1024, Ff,
        hbuf16, Ff, 0, Dm, elist, Nt, ecnt, 1, 1,
        nullptr, nullptr, nullptr, nullptr, nullptr, nullptr, 0, 0,
        nullptr, nullptr);
    // ffn2 + fused gate-combine: t2[token] += gate[pid] * (H[pid] @ w2[e] + b2[e])
    gemm_bf16_kernel<0, 1, 0, 1><<<dim3(8, 32, 8), blk, 0, stream>>>(
        hbuf16, Ff, w2, w2, w2, Dm, (size_t)Ff * Dm, b2, b2, b2, Dm,
        nullptr, Dm, 0, Ff, elist, Nt, ecnt, 2, 0,
        nullptr, nullptr, nullptr, nullptr, nullptr, nullptr, 0, 0,
        gatep, t2);
    ln_residual_kernel<<<Nt, blk, 0, stream>>>(tb, t2, ln3_g, ln3_b, outp);
    lb_kernel<<<1, 64, 0, stream>>>(impf, cntf, outp + ND);
}

// Round 9
// 790.320 us; speedup vs baseline: 1.0449x; 1.0449x over previous
//
#include <hip/hip_runtime.h>

// Problem constants
constexpr int Dm = 1024;
constexpr int NH = 16;
constexpr int Ff = 2048;
constexpr int NE = 8;
constexpr int Bn = 4;
constexpr int Tn = 512;
constexpr int Nt = 2048;   // total tokens

typedef float  f32x4  __attribute__((ext_vector_type(4)));
typedef __bf16 bf16x8 __attribute__((ext_vector_type(8)));
typedef unsigned short u16;
typedef u16 u16x8v __attribute__((ext_vector_type(8)));
typedef u16 u16x4v __attribute__((ext_vector_type(4)));

__device__ inline u16 f2bf(float f) {
    unsigned u = __builtin_bit_cast(unsigned, f);
    u += 0x7FFFu + ((u >> 16) & 1u);
    return (u16)(u >> 16);
}
__device__ inline float bf2f(u16 h) {
    unsigned u = (unsigned)h << 16;
    return __builtin_bit_cast(float, u);
}
__device__ inline void splitbf(float x, u16& hi, u16& lo) {
    hi = f2bf(x);
    lo = f2bf(x - bf2f(hi));
}
__device__ inline bf16x8 ld_frag(const u16* p) {
    return __builtin_bit_cast(bf16x8, *(const u16x8v*)p);
}
// async global->LDS 16B copy: per-lane global addr, wave-uniform LDS base
__device__ inline void cp16(const u16* g, u16* l) {
    __builtin_amdgcn_global_load_lds(
        (const __attribute__((address_space(1))) unsigned int*)g,
        (__attribute__((address_space(3))) unsigned int*)l, 16, 0, 0);
}

// ---------------------------------------------------------------------------
// m97-style MFMA GEMM. All operands pre-formatted bf16 (A row-major [m][k],
// W transposed [n][k], both hi/lo planes for SPLIT). Tile 128x128x32, 4 waves.
// K-loop: global_load_lds(16B) staging (zero cvt VALU), XOR-swizzled unpadded
// LDS (2-way conflicts only), ds_read_b128 frags, MFMA.
//  SPLIT: 3-term split-bf16. CMODE: 0 = f32 C, 1 = bf16 C, 2 = hi/lo planes,
//  3 = gated atomic accumulate (MoE combine). mode: 0 dense, 1 ffn1, 2 ffn2.
// Optional fused second dense GEMM (blockIdx.x >= xSplit).
// ---------------------------------------------------------------------------
template <int SPLIT, int CMODE>
__global__ __launch_bounds__(256) void gemm_kernel(
    const u16* __restrict__ Ahi, const u16* __restrict__ Alo, int lda,
    const u16* __restrict__ Whi, const u16* __restrict__ Wlo, size_t weStride,
    const float* __restrict__ B0, const float* __restrict__ B1,
    const float* __restrict__ B2, size_t beStride,
    void* __restrict__ C0, void* __restrict__ C1, int ldc,
    int Mparam, int K,
    const int* __restrict__ lst, int lstStride, const int* __restrict__ cnt,
    int mode, int relu,
    const u16* __restrict__ A2hi, const u16* __restrict__ A2lo, int lda2,
    const u16* __restrict__ W2hi, const u16* __restrict__ W2lo,
    const float* __restrict__ B20, const float* __restrict__ B21,
    void* __restrict__ C20, void* __restrict__ C21, int ldc2, int xSplit,
    const float* __restrict__ gatep, float* __restrict__ accOut)
{
    __shared__ __align__(16) u16 AsH[128 * 32];
    __shared__ __align__(16) u16 WsH[128 * 32];
    __shared__ __align__(16) u16 AsL[SPLIT ? 128 * 32 : 8];
    __shared__ __align__(16) u16 WsL[SPLIT ? 128 * 32 : 8];
    __shared__ int inIdx[128];
    __shared__ int outIdx[128];

    const int e = blockIdx.z;
    const int M = (mode == 0) ? Mparam : cnt[e];
    const int m0 = blockIdx.y * 128;
    if (m0 >= M) return;

    int bx = blockIdx.x;
    const u16 *aH = Ahi, *aL = Alo, *wH = Whi, *wL = Wlo;
    const float *b0 = B0, *b1 = B1, *b2 = B2;
    void *c0 = C0, *c1 = C1;
    int myLda = lda, myLdc = ldc;
    if (xSplit && bx >= xSplit) {
        bx -= xSplit;
        aH = A2hi; aL = A2lo; wH = W2hi; wL = W2lo;
        b0 = B20; b1 = B21; b2 = B21;
        c0 = C20; c1 = C21; myLda = lda2; myLdc = ldc2;
    }
    const int n0 = bx * 128;
    const int seg = n0 >> 10, nseg = n0 & 1023;
    const float* bias = ((seg == 0) ? b0 : (seg == 1) ? b1 : b2) + (size_t)e * beStride;
    const int tid = threadIdx.x;

    if (tid < 128) {
        int g = m0 + tid;
        bool valid = g < M;
        int gi, go;
        if (mode == 0) { gi = valid ? g : (M - 1); go = valid ? g : -1; }
        else {
            int pid = lst[(size_t)e * lstStride + (valid ? g : 0)];
            gi = (mode == 1) ? (pid >> 1) : pid;
            go = valid ? pid : -1;
        }
        inIdx[tid] = gi;
        outIdx[tid] = go;
    }
    __syncthreads();

    const int lane = tid & 63, wv = tid >> 6;
    // two 1-KB chunks per wave per plane; chunk c covers tile rows [c*16,c*16+16)
    const int c0i = wv * 2, c1i = wv * 2 + 1;
    const int r0 = c0i * 16 + (lane >> 2), r1 = c1i * 16 + (lane >> 2);
    const int kc0 = (lane & 3) ^ ((r0 >> 1) & 3);   // XOR swizzle (store side)
    const int kc1 = (lane & 3) ^ ((r1 >> 1) & 3);
    const size_t wOff = (size_t)e * weStride;
    const u16* aH0 = aH + (size_t)inIdx[r0] * myLda + kc0 * 8;
    const u16* aH1 = aH + (size_t)inIdx[r1] * myLda + kc1 * 8;
    const u16* wH0 = wH + wOff + (size_t)(n0 + r0) * K + kc0 * 8;
    const u16* wH1 = wH + wOff + (size_t)(n0 + r1) * K + kc1 * 8;
    const u16 *aL0 = nullptr, *aL1 = nullptr, *wL0 = nullptr, *wL1 = nullptr;
    if (SPLIT) {
        aL0 = aL + (size_t)inIdx[r0] * myLda + kc0 * 8;
        aL1 = aL + (size_t)inIdx[r1] * myLda + kc1 * 8;
        wL0 = wL + wOff + (size_t)(n0 + r0) * K + kc0 * 8;
        wL1 = wL + wOff + (size_t)(n0 + r1) * K + kc1 * 8;
    }
    u16* ldsA0 = &AsH[c0i * 512];
    u16* ldsA1 = &AsH[c1i * 512];
    u16* ldsW0 = &WsH[c0i * 512];
    u16* ldsW1 = &WsH[c1i * 512];
    u16* ldsAL0 = SPLIT ? &AsL[c0i * 512] : nullptr;
    u16* ldsAL1 = SPLIT ? &AsL[c1i * 512] : nullptr;
    u16* ldsWL0 = SPLIT ? &WsL[c0i * 512] : nullptr;
    u16* ldsWL1 = SPLIT ? &WsL[c1i * 512] : nullptr;

    const int wy = (wv >> 1) * 64, wx = (wv & 1) * 64;
    const int l15 = lane & 15, quad = lane >> 4;

    f32x4 acc[4][4];
    #pragma unroll
    for (int i = 0; i < 4; ++i)
        #pragma unroll
        for (int j = 0; j < 4; ++j) acc[i][j] = (f32x4)0.f;

    for (int k0 = 0; k0 < K; k0 += 32) {
        cp16(aH0 + k0, ldsA0);
        cp16(aH1 + k0, ldsA1);
        cp16(wH0 + k0, ldsW0);
        cp16(wH1 + k0, ldsW1);
        if (SPLIT) {
            cp16(aL0 + k0, ldsAL0);
            cp16(aL1 + k0, ldsAL1);
            cp16(wL0 + k0, ldsWL0);
            cp16(wL1 + k0, ldsWL1);
        }
        __syncthreads();   // waits vmcnt(0): staging complete

        bf16x8 ah[4], bh[4], al[4], bl[4];
        #pragma unroll
        for (int mi = 0; mi < 4; ++mi) {
            int r = wy + mi * 16 + l15;
            int sl = quad ^ ((r >> 1) & 3);        // XOR swizzle (read side)
            ah[mi] = ld_frag(&AsH[r * 32 + sl * 8]);
            if (SPLIT) al[mi] = ld_frag(&AsL[r * 32 + sl * 8]);
        }
        #pragma unroll
        for (int ni = 0; ni < 4; ++ni) {
            int r = wx + ni * 16 + l15;
            int sl = quad ^ ((r >> 1) & 3);
            bh[ni] = ld_frag(&WsH[r * 32 + sl * 8]);
            if (SPLIT) bl[ni] = ld_frag(&WsL[r * 32 + sl * 8]);
        }
        #pragma unroll
        for (int mi = 0; mi < 4; ++mi)
            #pragma unroll
            for (int ni = 0; ni < 4; ++ni) {
                acc[mi][ni] = __builtin_amdgcn_mfma_f32_16x16x32_bf16(
                    ah[mi], bh[ni], acc[mi][ni], 0, 0, 0);
                if (SPLIT) {
                    acc[mi][ni] = __builtin_amdgcn_mfma_f32_16x16x32_bf16(
                        ah[mi], bl[ni], acc[mi][ni], 0, 0, 0);
                    acc[mi][ni] = __builtin_amdgcn_mfma_f32_16x16x32_bf16(
                        al[mi], bh[ni], acc[mi][ni], 0, 0, 0);
                }
            }
        __syncthreads();
    }

    // ---- epilogue ----
    #pragma unroll
    for (int mi = 0; mi < 4; ++mi) {
        #pragma unroll
        for (int r = 0; r < 4; ++r) {
            int rl = wy + mi * 16 + quad * 4 + r;
            int orow = outIdx[rl];
            if (orow < 0) continue;
            #pragma unroll
            for (int ni = 0; ni < 4; ++ni) {
                int col = nseg + wx + ni * 16 + l15;
                float val = acc[mi][ni][r] + bias[col];
                if (relu) val = fmaxf(val, 0.f);
                int gcol = n0 + wx + ni * 16 + l15;
                if (CMODE == 3) {
                    atomicAdd(&accOut[(size_t)(orow >> 1) * Dm + gcol],
                              gatep[orow] * val);
                } else if (CMODE == 2) {
                    u16 hh, ll;
                    splitbf(val, hh, ll);
                    ((u16*)c0)[(size_t)orow * myLdc + gcol] = hh;
                    ((u16*)c1)[(size_t)orow * myLdc + gcol] = ll;
                } else if (CMODE == 1) {
                    ((u16*)c0)[(size_t)orow * myLdc + gcol] = f2bf(val);
                } else {
                    ((float*)c0)[(size_t)orow * myLdc + gcol] = val;
                }
            }
        }
    }
}

// ---------------------------------------------------------------------------
// Split-bf16 flash attention; Q/K/V read from pre-split bf16 planes (copy-only
// staging, zero cvt). Block = 64 Q rows x (b,h); 4 waves x 16 Q rows.
// Writes O as hi/lo bf16 planes.
// ---------------------------------------------------------------------------
__global__ __launch_bounds__(256) void attn_kernel(
    const u16* __restrict__ QH, const u16* __restrict__ QL, int qld, int qOff,
    const u16* __restrict__ KH, const u16* __restrict__ KL, int kld, int kOff,
    const u16* __restrict__ VH, const u16* __restrict__ VL, int vld, int vOff,
    u16* __restrict__ OH, u16* __restrict__ OL)
{
    __shared__ __align__(16) u16 KtH[64 * 72], KtL[64 * 72];
    __shared__ __align__(16) u16 VtH[64 * 72], VtL[64 * 72];
    __shared__ __align__(16) u16 PtH[4][16 * 72], PtL[4][16 * 72];

    const int tid = threadIdx.x, lane = tid & 63, wv = tid >> 6;
    const int quad = lane >> 4, l15 = lane & 15;
    const int b = blockIdx.z, h = blockIdx.y, q0 = blockIdx.x * 64;
    const int bT = b * Tn;

    bf16x8 aqh[2], aql[2];
    {
        size_t qbase = (size_t)(bT + q0 + wv * 16 + l15) * qld + qOff + h * 64;
        #pragma unroll
        for (int s = 0; s < 2; ++s) {
            aqh[s] = ld_frag(QH + qbase + s * 32 + quad * 8);
            aql[s] = ld_frag(QL + qbase + s * 32 + quad * 8);
        }
    }

    f32x4 oacc[4];
    #pragma unroll
    for (int i = 0; i < 4; ++i) oacc[i] = (f32x4)0.f;
    float mrow[4] = {-1e30f, -1e30f, -1e30f, -1e30f};
    float lrow[4] = {0.f, 0.f, 0.f, 0.f};

    const int rr = tid >> 2, cc = tid & 3;

    for (int kt0 = 0; kt0 < Tn; kt0 += 64) {
        // ---- stage K [kt][d], V transposed [d][kt]: pure copies ----
        {
            size_t kb = (size_t)(bT + kt0 + rr) * kld + kOff + h * 64 + cc * 16;
            *(u16x8v*)&KtH[rr * 72 + cc * 16]     = *(const u16x8v*)(KH + kb);
            *(u16x8v*)&KtH[rr * 72 + cc * 16 + 8] = *(const u16x8v*)(KH + kb + 8);
            *(u16x8v*)&KtL[rr * 72 + cc * 16]     = *(const u16x8v*)(KL + kb);
            *(u16x8v*)&KtL[rr * 72 + cc * 16 + 8] = *(const u16x8v*)(KL + kb + 8);

            size_t vb = (size_t)(bT + kt0 + rr) * vld + vOff + h * 64 + cc * 16;
            u16x8v va = *(const u16x8v*)(VH + vb);
            u16x8v vbv = *(const u16x8v*)(VH + vb + 8);
            u16x8v la = *(const u16x8v*)(VL + vb);
            u16x8v lb = *(const u16x8v*)(VL + vb + 8);
            #pragma unroll
            for (int i = 0; i < 8; ++i) {
                VtH[(cc * 16 + i) * 72 + rr]     = va[i];
                VtH[(cc * 16 + 8 + i) * 72 + rr] = vbv[i];
                VtL[(cc * 16 + i) * 72 + rr]     = la[i];
                VtL[(cc * 16 + 8 + i) * 72 + rr] = lb[i];
            }
        }
        __syncthreads();

        // ---- S = (Q K^T) * 0.125, split 3-term ----
        f32x4 sacc[4];
        #pragma unroll
        for (int nt = 0; nt < 4; ++nt) {
            sacc[nt] = (f32x4)0.f;
            #pragma unroll
            for (int s = 0; s < 2; ++s) {
                bf16x8 bkh = ld_frag(&KtH[(nt * 16 + l15) * 72 + s * 32 + quad * 8]);
                bf16x8 bkl = ld_frag(&KtL[(nt * 16 + l15) * 72 + s * 32 + quad * 8]);
                sacc[nt] = __builtin_amdgcn_mfma_f32_16x16x32_bf16(aqh[s], bkh, sacc[nt], 0, 0, 0);
                sacc[nt] = __builtin_amdgcn_mfma_f32_16x16x32_bf16(aqh[s], bkl, sacc[nt], 0, 0, 0);
                sacc[nt] = __builtin_amdgcn_mfma_f32_16x16x32_bf16(aql[s], bkh, sacc[nt], 0, 0, 0);
            }
        }
        #pragma unroll
        for (int nt = 0; nt < 4; ++nt)
            #pragma unroll
            for (int r = 0; r < 4; ++r) sacc[nt][r] *= 0.125f;

        // ---- online softmax ----
        float alpha[4], mnew[4];
        #pragma unroll
        for (int r = 0; r < 4; ++r) {
            float mx = fmaxf(fmaxf(sacc[0][r], sacc[1][r]), fmaxf(sacc[2][r], sacc[3][r]));
            #pragma unroll
            for (int msk = 1; msk < 16; msk <<= 1) mx = fmaxf(mx, __shfl_xor(mx, msk));
            mnew[r] = fmaxf(mrow[r], mx);
            alpha[r] = __expf(mrow[r] - mnew[r]);
            mrow[r] = mnew[r];
        }
        float rs[4] = {0.f, 0.f, 0.f, 0.f};
        #pragma unroll
        for (int nt = 0; nt < 4; ++nt)
            #pragma unroll
            for (int r = 0; r < 4; ++r) {
                float p = __expf(sacc[nt][r] - mnew[r]);
                sacc[nt][r] = p;
                rs[r] += p;
            }
        #pragma unroll
        for (int r = 0; r < 4; ++r) {
            #pragma unroll
            for (int msk = 1; msk < 16; msk <<= 1) rs[r] += __shfl_xor(rs[r], msk);
            lrow[r] = lrow[r] * alpha[r] + rs[r];
        }
        #pragma unroll
        for (int ni = 0; ni < 4; ++ni)
            #pragma unroll
            for (int r = 0; r < 4; ++r) oacc[ni][r] *= alpha[r];

        // ---- P: C-layout -> A-layout via per-wave LDS (hi/lo) ----
        #pragma unroll
        for (int nt = 0; nt < 4; ++nt)
            #pragma unroll
            for (int r = 0; r < 4; ++r) {
                u16 hh, ll;
                splitbf(sacc[nt][r], hh, ll);
                PtH[wv][(quad * 4 + r) * 72 + nt * 16 + l15] = hh;
                PtL[wv][(quad * 4 + r) * 72 + nt * 16 + l15] = ll;
            }
        asm volatile("s_waitcnt lgkmcnt(0)" ::: "memory");

        // ---- O += P @ V, split 3-term ----
        #pragma unroll
        for (int s = 0; s < 2; ++s) {
            bf16x8 aph = ld_frag(&PtH[wv][l15 * 72 + s * 32 + quad * 8]);
            bf16x8 apl = ld_frag(&PtL[wv][l15 * 72 + s * 32 + quad * 8]);
            #pragma unroll
            for (int ni = 0; ni < 4; ++ni) {
                bf16x8 bvh = ld_frag(&VtH[(ni * 16 + l15) * 72 + s * 32 + quad * 8]);
                bf16x8 bvl = ld_frag(&VtL[(ni * 16 + l15) * 72 + s * 32 + quad * 8]);
                oacc[ni] = __builtin_amdgcn_mfma_f32_16x16x32_bf16(aph, bvh, oacc[ni], 0, 0, 0);
                oacc[ni] = __builtin_amdgcn_mfma_f32_16x16x32_bf16(aph, bvl, oacc[ni], 0, 0, 0);
                oacc[ni] = __builtin_amdgcn_mfma_f32_16x16x32_bf16(apl, bvh, oacc[ni], 0, 0, 0);
            }
        }
        __syncthreads();
    }

    #pragma unroll
    for (int r = 0; r < 4; ++r) {
        float inv = 1.f / lrow[r];
        int orow = bT + q0 + wv * 16 + quad * 4 + r;
        #pragma unroll
        for (int ni = 0; ni < 4; ++ni) {
            int col = h * 64 + ni * 16 + l15;
            u16 hh, ll;
            splitbf(oacc[ni][r] * inv, hh, ll);
            OH[(size_t)orow * Dm + col] = hh;
            OL[(size_t)orow * Dm + col] = ll;
        }
    }
}

// ---------------------------------------------------------------------------
// Fused residual + LayerNorm; optionally emits bf16 hi/lo planes too.
// ---------------------------------------------------------------------------
__global__ __launch_bounds__(256) void ln_residual_kernel(
    const float* __restrict__ X, const float* __restrict__ R,
    const float* __restrict__ g, const float* __restrict__ bta,
    float* __restrict__ Out, u16* __restrict__ outH, u16* __restrict__ outL)
{
    __shared__ float red[8];
    const int t = blockIdx.x, tid = threadIdx.x;
    float v[4];
    float s = 0.f;
    #pragma unroll
    for (int i = 0; i < 4; ++i) {
        int c = tid + i * 256;
        v[i] = X[(size_t)t * Dm + c] + R[(size_t)t * Dm + c];
        s += v[i];
    }
    #pragma unroll
    for (int off = 32; off; off >>= 1) s += __shfl_down(s, off);
    const int wid = tid >> 6;
    if ((tid & 63) == 0) red[wid] = s;
    __syncthreads();
    const float mean = (red[0] + red[1] + red[2] + red[3]) * (1.f / 1024.f);
    float s2 = 0.f;
    #pragma unroll
    for (int i = 0; i < 4; ++i) { float d = v[i] - mean; s2 += d * d; }
    #pragma unroll
    for (int off = 32; off; off >>= 1) s2 += __shfl_down(s2, off);
    if ((tid & 63) == 0) red[4 + wid] = s2;
    __syncthreads();
    const float var  = (red[4] + red[5] + red[6] + red[7]) * (1.f / 1024.f);
    const float rstd = rsqrtf(var + 1e-5f);
    #pragma unroll
    for (int i = 0; i < 4; ++i) {
        int c = tid + i * 256;
        float o = (v[i] - mean) * rstd * g[c] + bta[c];
        Out[(size_t)t * Dm + c] = o;
        if (outH) {
            u16 hh, ll;
            splitbf(o, hh, ll);
            outH[(size_t)t * Dm + c] = hh;
            outL[(size_t)t * Dm + c] = ll;
        }
    }
}

// ---------------------------------------------------------------------------
// Prep: fp32 -> bf16 hi/lo planes (4 elems per thread)
// ---------------------------------------------------------------------------
__global__ __launch_bounds__(256) void split_kernel(
    const float* __restrict__ src, u16* __restrict__ hi, u16* __restrict__ lo)
{
    int i = (blockIdx.x * 256 + threadIdx.x) * 4;
    float4 v = *(const float4*)(src + i);
    u16x4v h, l;
    u16 hh, ll;
    splitbf(v.x, hh, ll); h[0] = hh; l[0] = ll;
    splitbf(v.y, hh, ll); h[1] = hh; l[1] = ll;
    splitbf(v.z, hh, ll); h[2] = hh; l[2] = ll;
    splitbf(v.w, hh, ll); h[3] = hh; l[3] = ll;
    *(u16x4v*)(hi + i) = h;
    *(u16x4v*)(lo + i) = l;
}

// ---------------------------------------------------------------------------
// Prep: weight transpose + bf16 split. src [Ksrc][Nsrc] fp32 -> dst [Nsrc][Ksrc]
// bf16 hi (+lo if non-null). blockIdx.z = expert (strides) for MoE.
// ---------------------------------------------------------------------------
__global__ __launch_bounds__(256) void wT_kernel(
    const float* __restrict__ src, size_t srcEStride, int Ksrc, int Nsrc,
    u16* __restrict__ dhi, u16* __restrict__ dlo, size_t dstEStride)
{
    __shared__ float tile[64][65];
    const int e = blockIdx.z;
    src += (size_t)e * srcEStride;
    dhi += (size_t)e * dstEStride;
    if (dlo) dlo += (size_t)e * dstEStride;
    const int n0 = blockIdx.x * 64, k0 = blockIdx.y * 64;
    for (int i = threadIdx.x; i < 4096; i += 256) {
        int r = i >> 6, c = i & 63;   // r = k-local, c = n-local
        tile[r][c] = src[(size_t)(k0 + r) * Nsrc + n0 + c];
    }
    __syncthreads();
    for (int i = threadIdx.x; i < 4096; i += 256) {
        int r = i >> 6, c = i & 63;   // r = n-local, c = k-local
        float v = tile[c][r];
        u16 hh, ll;
        splitbf(v, hh, ll);
        dhi[(size_t)(n0 + r) * Ksrc + k0 + c] = hh;
        if (dlo) dlo[(size_t)(n0 + r) * Ksrc + k0 + c] = ll;
    }
}

// ---------------------------------------------------------------------------
// MoE router — LDS-aggregated stats, block-batched atomics.
// ---------------------------------------------------------------------------
constexpr int RT_TPB = 32;
__global__ __launch_bounds__(256) void router_kernel(
    const float* __restrict__ X, const float* __restrict__ rw,
    const float* __restrict__ rb, float* __restrict__ gatep,
    int* __restrict__ elist, int* __restrict__ ecnt,
    float* __restrict__ impf, float* __restrict__ cntf)
{
    __shared__ float simp[NE];
    __shared__ int   scnt[NE];
    __shared__ int   sbase[NE];
    __shared__ int   sexp[RT_TPB][2];
    __shared__ int   spos[RT_TPB][2];

    const int tid = threadIdx.x, lane = tid & 63, wv = tid >> 6;
    if (tid < NE) { simp[tid] = 0.f; scnt[tid] = 0; }
    __syncthreads();

    const int t0 = blockIdx.x * RT_TPB;

    for (int i = 0; i < 8; ++i) {
        const int slot = wv * 8 + i;
        const int t = t0 + slot;
        float l[NE];
        #pragma unroll
        for (int e = 0; e < NE; ++e) l[e] = 0.f;
        #pragma unroll
        for (int j = 0; j < Dm / 64; ++j) {
            int d = lane + j * 64;
            float x = X[(size_t)t * Dm + d];
            #pragma unroll
            for (int e = 0; e < NE; ++e) l[e] += x * rw[d * NE + e];
        }
        #pragma unroll
        for (int e = 0; e < NE; ++e) {
            float vv = l[e];
            #pragma unroll
            for (int off = 32; off; off >>= 1) vv += __shfl_down(vv, off);
            l[e] = vv;
        }
        if (lane == 0) {
            float mx = -1e30f;
            #pragma unroll
            for (int e = 0; e < NE; ++e) { l[e] += rb[e]; mx = fmaxf(mx, l[e]); }
            float p[NE];
            float sum = 0.f;
            #pragma unroll
            for (int e = 0; e < NE; ++e) { p[e] = __expf(l[e] - mx); sum += p[e]; }
            const float inv = 1.f / sum;
            int e0 = 0, e1 = 0;
            float v0 = -1.f, v1 = -1.f;
            #pragma unroll
            for (int e = 0; e < NE; ++e) {
                float pe = p[e] * inv;
                atomicAdd(&simp[e], pe);
                if (pe > v0)      { v1 = v0; e1 = e0; v0 = pe; e0 = e; }
                else if (pe > v1) { v1 = pe; e1 = e; }
            }
            const float gs = 1.f / (v0 + v1);
            sexp[slot][0] = e0;
            sexp[slot][1] = e1;
            spos[slot][0] = atomicAdd(&scnt[e0], 1);
            spos[slot][1] = atomicAdd(&scnt[e1], 1);
            gatep[2 * t]     = v0 * gs;
            gatep[2 * t + 1] = v1 * gs;
        }
    }
    __syncthreads();

    if (tid < NE) {
        sbase[tid] = atomicAdd(&ecnt[tid], scnt[tid]);
        atomicAdd(&impf[tid], simp[tid]);
        atomicAdd(&cntf[tid], (float)scnt[tid]);
    }
    __syncthreads();

    if (tid < RT_TPB * 2) {
        const int slot = tid >> 1, k = tid & 1;
        const int e = sexp[slot][k];
        elist[e * Nt + sbase[e] + spos[slot][k]] = 2 * (t0 + slot) + k;
    }
}

__global__ __launch_bounds__(256) void zero_kernel(
    float* __restrict__ t2, int* __restrict__ ecnt,
    float* __restrict__ impf, float* __restrict__ cntf)
{
    int i = blockIdx.x * 256 + threadIdx.x;
    *(float4*)&t2[(size_t)i * 4] = make_float4(0.f, 0.f, 0.f, 0.f);
    if (blockIdx.x == 0 && threadIdx.x < NE) {
        ecnt[threadIdx.x] = 0;
        impf[threadIdx.x] = 0.f;
        cntf[threadIdx.x] = 0.f;
    }
}

__global__ void lb_kernel(const float* __restrict__ impf,
                          const float* __restrict__ cntf,
                          float* __restrict__ out)
{
    if (threadIdx.x == 0) {
        float s = 0.f;
        for (int e = 0; e < NE; ++e) s += cntf[e] * impf[e];
        out[0] = (float)NE * s / ((float)Nt * 2.f * (float)Nt);
    }
}

// ---------------------------------------------------------------------------
extern "C" void kernel_launch(void* const* d_in, const int* in_sizes, int n_in,
                              void* d_out, int out_size, void* d_ws, size_t ws_size,
                              hipStream_t stream)
{
    const float* tgt   = (const float*)d_in[0];
    const float* memry = (const float*)d_in[1];
    const float* sa_wq = (const float*)d_in[2];
    const float* sa_wk = (const float*)d_in[3];
    const float* sa_wv = (const float*)d_in[4];
    const float* sa_wo = (const float*)d_in[5];
    const float* ca_wq = (const float*)d_in[6];
    const float* ca_wk = (const float*)d_in[7];
    const float* ca_wv = (const float*)d_in[8];
    const float* ca_wo = (const float*)d_in[9];
    const float* sa_bq = (const float*)d_in[10];
    const float* sa_bk = (const float*)d_in[11];
    const float* sa_bv = (const float*)d_in[12];
    const float* sa_bo = (const float*)d_in[13];
    const float* ca_bq = (const float*)d_in[14];
    const float* ca_bk = (const float*)d_in[15];
    const float* ca_bv = (const float*)d_in[16];
    const float* ca_bo = (const float*)d_in[17];
    const float* ln1_g = (const float*)d_in[18];
    const float* ln2_g = (const float*)d_in[19];
    const float* ln3_g = (const float*)d_in[20];
    const float* ln1_b = (const float*)d_in[21];
    const float* ln2_b = (const float*)d_in[22];
    const float* ln3_b = (const float*)d_in[23];
    const float* rw    = (const float*)d_in[24];
    const float* rb    = (const float*)d_in[25];
    const float* w1    = (const float*)d_in[26];
    const float* b1    = (const float*)d_in[27];
    const float* w2    = (const float*)d_in[28];
    const float* b2    = (const float*)d_in[29];

    const size_t ND = (size_t)Nt * Dm;   // 2.10M
    const size_t MM = (size_t)1024 * 1024;
    u16* U = (u16*)d_ws;
    size_t off = 0;
    auto A = [&](size_t n) { u16* p = U + off; off += n; return p; };
    // weight planes (transposed [n][k])
    u16* qkvT_h  = A(3 * MM);  u16* qkvT_l  = A(3 * MM);
    u16* cakvT_h = A(2 * MM);  u16* cakvT_l = A(2 * MM);
    u16* caqT_h  = A(MM);      u16* caqT_l  = A(MM);
    u16* saoT_h  = A(MM);      u16* saoT_l  = A(MM);
    u16* caoT_h  = A(MM);      u16* caoT_l  = A(MM);
    u16* w1t     = A(16 * MM);
    u16* w2t     = A(16 * MM);
    // activation planes
    u16* tgtH = A(ND);  u16* tgtL = A(ND);   // reused as qcH/qcL
    u16* memH = A(ND);  u16* memL = A(ND);   // reused as aoH/aoL
    u16* qkvH = A(3 * ND);  u16* qkvL = A(3 * ND);  // hbuf aliases here
    u16* kvcH = A(2 * ND);  u16* kvcL = A(2 * ND);
    u16* tbH  = A(ND);  u16* tbL = A(ND);
    u16* qcH = tgtH, *qcL = tgtL;
    u16* aoH = memH, *aoL = memL;
    u16* hbuf = qkvH;   // 4096 x 2048 bf16 = 4*ND u16, fits in qkvH+qkvL (6*ND)
    // fp32 region
    float* Fp = (float*)(U + off);
    float* t2 = Fp;
    float* tb = Fp + ND;
    float* gatep = tb + ND;
    int*   elist = (int*)(gatep + 2 * Nt);
    int*   ecnt  = elist + NE * Nt;
    float* impf  = (float*)(ecnt + NE);
    float* cntf  = impf + NE;
    float* outp  = (float*)d_out;

    dim3 blk(256);
    dim3 attnGrid(Tn / 64, NH, Bn);
    dim3 wtG(16, 16, 1);

    // ================= prep =================
    split_kernel<<<ND / 1024, blk, 0, stream>>>(tgt, tgtH, tgtL);
    split_kernel<<<ND / 1024, blk, 0, stream>>>(memry, memH, memL);
    wT_kernel<<<wtG, blk, 0, stream>>>(sa_wq, 0, 1024, 1024, qkvT_h,          qkvT_l,          0);
    wT_kernel<<<wtG, blk, 0, stream>>>(sa_wk, 0, 1024, 1024, qkvT_h + MM,     qkvT_l + MM,     0);
    wT_kernel<<<wtG, blk, 0, stream>>>(sa_wv, 0, 1024, 1024, qkvT_h + 2 * MM, qkvT_l + 2 * MM, 0);
    wT_kernel<<<wtG, blk, 0, stream>>>(ca_wk, 0, 1024, 1024, cakvT_h,         cakvT_l,         0);
    wT_kernel<<<wtG, blk, 0, stream>>>(ca_wv, 0, 1024, 1024, cakvT_h + MM,    cakvT_l + MM,    0);
    wT_kernel<<<wtG, blk, 0, stream>>>(ca_wq, 0, 1024, 1024, caqT_h, caqT_l, 0);
    wT_kernel<<<wtG, blk, 0, stream>>>(sa_wo, 0, 1024, 1024, saoT_h, saoT_l, 0);
    wT_kernel<<<wtG, blk, 0, stream>>>(ca_wo, 0, 1024, 1024, caoT_h, caoT_l, 0);
    wT_kernel<<<dim3(32, 16, 8), blk, 0, stream>>>(w1, 2 * MM, 1024, 2048, w1t, nullptr, 2 * MM);
    wT_kernel<<<dim3(16, 32, 8), blk, 0, stream>>>(w2, 2 * MM, 2048, 1024, w2t, nullptr, 2 * MM);

    // ============ self-attention ============
    // fused: self QKV (x<24) + cross KV (x>=24)
    gemm_kernel<1, 2><<<dim3(40, 16, 1), blk, 0, stream>>>(
        tgtH, tgtL, 1024, qkvT_h, qkvT_l, 0, sa_bq, sa_bk, sa_bv, 0,
        qkvH, qkvL, 3072, Nt, 1024, nullptr, 0, nullptr, 0, 0,
        memH, memL, 1024, cakvT_h, cakvT_l, ca_bk, ca_bv,
        kvcH, kvcL, 2048, 24, nullptr, nullptr);
    attn_kernel<<<attnGrid, blk, 0, stream>>>(
        qkvH, qkvL, 3072, 0, qkvH, qkvL, 3072, 1024, qkvH, qkvL, 3072, 2048,
        aoH, aoL);
    gemm_kernel<1, 0><<<dim3(8, 16, 1), blk, 0, stream>>>(
        aoH, aoL, 1024, saoT_h, saoT_l, 0, sa_bo, sa_bo, sa_bo, 0,
        t2, nullptr, 1024, Nt, 1024, nullptr, 0, nullptr, 0, 0,
        nullptr, nullptr, 0, nullptr, nullptr, nullptr, nullptr,
        nullptr, nullptr, 0, 0, nullptr, nullptr);
    ln_residual_kernel<<<Nt, blk, 0, stream>>>(tgt, t2, ln1_g, ln1_b, tb, tbH, tbL);

    // ============ cross-attention ============
    gemm_kernel<1, 2><<<dim3(8, 16, 1), blk, 0, stream>>>(
        tbH, tbL, 1024, caqT_h, caqT_l, 0, ca_bq, ca_bq, ca_bq, 0,
        qcH, qcL, 1024, Nt, 1024, nullptr, 0, nullptr, 0, 0,
        nullptr, nullptr, 0, nullptr, nullptr, nullptr, nullptr,
        nullptr, nullptr, 0, 0, nullptr, nullptr);
    attn_kernel<<<attnGrid, blk, 0, stream>>>(
        qcH, qcL, 1024, 0, kvcH, kvcL, 2048, 0, kvcH, kvcL, 2048, 1024,
        aoH, aoL);
    gemm_kernel<1, 0><<<dim3(8, 16, 1), blk, 0, stream>>>(
        aoH, aoL, 1024, caoT_h, caoT_l, 0, ca_bo, ca_bo, ca_bo, 0,
        t2, nullptr, 1024, Nt, 1024, nullptr, 0, nullptr, 0, 0,
        nullptr, nullptr, 0, nullptr, nullptr, nullptr, nullptr,
        nullptr, nullptr, 0, 0, nullptr, nullptr);
    ln_residual_kernel<<<Nt, blk, 0, stream>>>(tb, t2, ln2_g, ln2_b, tb, tbH, tbL);

    // ================= MoE =================
    zero_kernel<<<(Nt * Dm) / 1024, blk, 0, stream>>>(t2, ecnt, impf, cntf);
    router_kernel<<<Nt / RT_TPB, blk, 0, stream>>>(tb, rw, rb, gatep, elist, ecnt, impf, cntf);
    // ffn1: H[pid] = relu(tb[pid>>1] @ w1[e] + b1[e]) -> bf16
    gemm_kernel<0, 1><<<dim3(16, 16, 8), blk, 0, stream>>>(
        tbH, nullptr, 1024, w1t, nullptr, 2 * MM, b1, b1 + 1024, b1 + 1024, Ff,
        hbuf, nullptr, 2048, 0, 1024, elist, Nt, ecnt, 1, 1,
        nullptr, nullptr, 0, nullptr, nullptr, nullptr, nullptr,
        nullptr, nullptr, 0, 0, nullptr, nullptr);
    // ffn2 + fused gate-combine: t2[token] += gate[pid] * (H[pid] @ w2[e] + b2[e])
    gemm_kernel<0, 3><<<dim3(8, 16, 8), blk, 0, stream>>>(
        hbuf, nullptr, 2048, w2t, nullptr, 2 * MM, b2, b2, b2, Dm,
        nullptr, nullptr, 1024, 0, 2048, elist, Nt, ecnt, 2, 0,
        nullptr, nullptr, 0, nullptr, nullptr, nullptr, nullptr,
        nullptr, nullptr, 0, 0, gatep, t2);
    ln_residual_kernel<<<Nt, blk, 0, stream>>>(tb, t2, ln3_g, ln3_b, outp, nullptr, nullptr);
    lb_kernel<<<1, 64, 0, stream>>>(impf, cntf, outp + ND);
}